// Round 1
// baseline (656.852 us; speedup 1.0000x reference)
//
#include <hip/hip_runtime.h>

#define HIDDEN 4096
#define NH 32
#define NKV 8
#define HD 128
#define SKV 8192
#define SPLITS 16
#define KPS 513          // ceil(8193/16)
#define NPART 64         // SPLITS * 4 waves
#define PSTRIDE 520      // 4 m + 4 l + 4*128 acc

__device__ __forceinline__ float4 ld4(const float* p){ return *(const float4*)p; }

// ---------------- GEMV partial: out[c][b][j] = sum_{i in chunk c} vec[b][i]*mat[i][j]
__global__ __launch_bounds__(256) void gemv_part(const float* __restrict__ vec,
                                                 const float* __restrict__ mat,
                                                 float* __restrict__ part)
{
    const int jb  = blockIdx.x;          // 0..3
    const int c   = blockIdx.y;          // 0..63
    const int tid = threadIdx.x;
    const int j0  = jb*1024 + tid*4;

    __shared__ float hid[8*64];
    {
        int i = tid*2;
        hid[i]   = vec[(size_t)(i>>6)*HIDDEN     + c*64 + (i&63)];
        hid[i+1] = vec[(size_t)((i+1)>>6)*HIDDEN + c*64 + ((i+1)&63)];
    }
    __syncthreads();

    float4 acc[8];
#pragma unroll
    for (int b=0;b<8;b++) acc[b] = make_float4(0.f,0.f,0.f,0.f);

    const float* mp = mat + (size_t)c*64*HIDDEN + j0;
#pragma unroll 8
    for (int ii=0; ii<64; ii++) {
        float4 w = ld4(mp + (size_t)ii*HIDDEN);
#pragma unroll
        for (int b=0;b<8;b++) {
            float h = hid[b*64+ii];
            acc[b].x += h*w.x; acc[b].y += h*w.y;
            acc[b].z += h*w.z; acc[b].w += h*w.w;
        }
    }
#pragma unroll
    for (int b=0;b<8;b++)
        *(float4*)(part + ((size_t)(c*8+b))*HIDDEN + j0) = acc[b];
}

// ---------------- reduce q partials + RoPE
__global__ __launch_bounds__(256) void q_reduce_rope(const float* __restrict__ part,
                                                     const float* __restrict__ cosb,
                                                     const float* __restrict__ sinb,
                                                     float* __restrict__ q_rope)
{
    const int b   = blockIdx.x >> 3;
    const int seg = blockIdx.x & 7;
    const int lj  = threadIdx.x*2;
    const int j   = seg*512 + lj;

    float a0 = 0.f, a1 = 0.f;
    const float* pp = part + (size_t)b*HIDDEN + j;
#pragma unroll 4
    for (int c=0;c<64;c++){
        float2 v = *(const float2*)(pp + (size_t)c*8*HIDDEN);
        a0 += v.x; a1 += v.y;
    }
    __shared__ float lds[512];
    lds[lj] = a0; lds[lj+1] = a1;
    __syncthreads();

    const int d0 = j & 127;
    float p0 = lds[lj^64], p1 = lds[(lj^64)+1];
    float c0 = cosb[b*HD + d0], c1 = cosb[b*HD + d0 + 1];
    float s0 = sinb[b*HD + d0], s1 = sinb[b*HD + d0 + 1];
    float r0 = (d0 < 64) ? (a0*c0 - p0*s0) : (a0*c0 + p0*s0);
    float r1 = (d0 < 64) ? (a1*c1 - p1*s1) : (a1*c1 + p1*s1);
    q_rope[(size_t)b*HIDDEN + j]     = r0;
    q_rope[(size_t)b*HIDDEN + j + 1] = r1;
}

// ---------------- attention split kernel (flash-decoding)
// lane layout: kg = lane>>4 (key within 4-key group), dl = lane&15
// lane holds dims [dl*4, dl*4+4) and [64+dl*4, 64+dl*4+4)
__global__ __launch_bounds__(256) void attn_split(const float* __restrict__ qr,
                                                  const float* __restrict__ kc,
                                                  const float* __restrict__ vc,
                                                  const float* __restrict__ knew,
                                                  const float* __restrict__ vnew,
                                                  const float* __restrict__ cosb,
                                                  const float* __restrict__ sinb,
                                                  float* __restrict__ part)
{
    const int split = blockIdx.x;
    const int n     = blockIdx.y;
    const int b     = blockIdx.z;
    const int tid   = threadIdx.x;
    const int wave  = tid >> 6;
    const int lane  = tid & 63;
    const int kg    = lane >> 4;
    const int dl    = lane & 15;
    const float scale = 0.08838834764831845f;  // 128^-0.5

    float4 q1[4], q2[4];
    const float* qb = qr + ((size_t)b*NH + n*4)*HD;
#pragma unroll
    for (int h=0;h<4;h++){
        float4 x = ld4(qb + h*HD + dl*4);
        float4 y = ld4(qb + h*HD + 64 + dl*4);
        q1[h] = make_float4(x.x*scale, x.y*scale, x.z*scale, x.w*scale);
        q2[h] = make_float4(y.x*scale, y.y*scale, y.z*scale, y.w*scale);
    }
    float m[4], l[4];
    float4 acc1[4], acc2[4];
#pragma unroll
    for (int h=0;h<4;h++){
        m[h] = -1e30f; l[h] = 0.f;
        acc1[h] = make_float4(0.f,0.f,0.f,0.f);
        acc2[h] = make_float4(0.f,0.f,0.f,0.f);
    }

    const int k0   = split*KPS;
    const int kend = min(k0 + KPS, SKV + 1);

    for (int t0 = k0 + wave*16; t0 < kend; t0 += 64) {
        float s[4][4];
        float vmask[4];
#pragma unroll
        for (int it=0; it<4; it++){
            const int k = t0 + it*4 + kg;
            const bool valid = k < kend;
            vmask[it] = valid ? 1.f : 0.f;
            float4 k1 = make_float4(0.f,0.f,0.f,0.f), k2 = k1;
            if (valid) {
                if (k < SKV) {
                    const float* kp = kc + (((size_t)b*SKV + k)*NKV + n)*HD;
                    k1 = ld4(kp + dl*4);
                    k2 = ld4(kp + 64 + dl*4);
                } else {
                    const float* kp = knew + ((size_t)b*NKV + n)*HD;
                    float4 f1 = ld4(kp + dl*4);
                    float4 f2 = ld4(kp + 64 + dl*4);
                    float4 c1 = ld4(cosb + b*HD + dl*4);
                    float4 s1 = ld4(sinb + b*HD + dl*4);
                    float4 c2 = ld4(cosb + b*HD + 64 + dl*4);
                    float4 s2 = ld4(sinb + b*HD + 64 + dl*4);
                    k1 = make_float4(f1.x*c1.x - f2.x*s1.x, f1.y*c1.y - f2.y*s1.y,
                                     f1.z*c1.z - f2.z*s1.z, f1.w*c1.w - f2.w*s1.w);
                    k2 = make_float4(f2.x*c2.x + f1.x*s2.x, f2.y*c2.y + f1.y*s2.y,
                                     f2.z*c2.z + f1.z*s2.z, f2.w*c2.w + f1.w*s2.w);
                }
            }
#pragma unroll
            for (int h=0;h<4;h++){
                float sp = q1[h].x*k1.x + q1[h].y*k1.y + q1[h].z*k1.z + q1[h].w*k1.w
                         + q2[h].x*k2.x + q2[h].y*k2.y + q2[h].z*k2.z + q2[h].w*k2.w;
                sp += __shfl_xor(sp, 1);
                sp += __shfl_xor(sp, 2);
                sp += __shfl_xor(sp, 4);
                sp += __shfl_xor(sp, 8);
                s[h][it] = valid ? sp : -1e30f;
            }
        }
        float p[4][4];
#pragma unroll
        for (int h=0;h<4;h++){
            float mn = fmaxf(fmaxf(s[h][0], s[h][1]), fmaxf(s[h][2], s[h][3]));
            mn = fmaxf(m[h], mn);
            float alpha = __expf(m[h] - mn);
            float ps = 0.f;
#pragma unroll
            for (int it=0; it<4; it++){
                p[h][it] = __expf(s[h][it] - mn) * vmask[it];
                ps += p[h][it];
            }
            l[h] = l[h]*alpha + ps;
            acc1[h].x *= alpha; acc1[h].y *= alpha; acc1[h].z *= alpha; acc1[h].w *= alpha;
            acc2[h].x *= alpha; acc2[h].y *= alpha; acc2[h].z *= alpha; acc2[h].w *= alpha;
            m[h] = mn;
        }
#pragma unroll
        for (int it=0; it<4; it++){
            const int k = t0 + it*4 + kg;
            if (k < kend) {
                const float* vp = (k < SKV) ? vc + (((size_t)b*SKV + k)*NKV + n)*HD
                                            : vnew + ((size_t)b*NKV + n)*HD;
                float4 v1 = ld4(vp + dl*4);
                float4 v2 = ld4(vp + 64 + dl*4);
#pragma unroll
                for (int h=0;h<4;h++){
                    float ph = p[h][it];
                    acc1[h].x += ph*v1.x; acc1[h].y += ph*v1.y;
                    acc1[h].z += ph*v1.z; acc1[h].w += ph*v1.w;
                    acc2[h].x += ph*v2.x; acc2[h].y += ph*v2.y;
                    acc2[h].z += ph*v2.z; acc2[h].w += ph*v2.w;
                }
            }
        }
    }

    // combine the 4 key-groups within the wave (lanes xor 16, 32)
#pragma unroll
    for (int h=0;h<4;h++){
        float M = m[h];
        M = fmaxf(M, __shfl_xor(M, 16));
        M = fmaxf(M, __shfl_xor(M, 32));
        float sc = __expf(m[h] - M);
        float lh = l[h]*sc;
        lh += __shfl_xor(lh, 16);
        lh += __shfl_xor(lh, 32);
        float t;
        t = acc1[h].x*sc; t += __shfl_xor(t,16); t += __shfl_xor(t,32); acc1[h].x = t;
        t = acc1[h].y*sc; t += __shfl_xor(t,16); t += __shfl_xor(t,32); acc1[h].y = t;
        t = acc1[h].z*sc; t += __shfl_xor(t,16); t += __shfl_xor(t,32); acc1[h].z = t;
        t = acc1[h].w*sc; t += __shfl_xor(t,16); t += __shfl_xor(t,32); acc1[h].w = t;
        t = acc2[h].x*sc; t += __shfl_xor(t,16); t += __shfl_xor(t,32); acc2[h].x = t;
        t = acc2[h].y*sc; t += __shfl_xor(t,16); t += __shfl_xor(t,32); acc2[h].y = t;
        t = acc2[h].z*sc; t += __shfl_xor(t,16); t += __shfl_xor(t,32); acc2[h].z = t;
        t = acc2[h].w*sc; t += __shfl_xor(t,16); t += __shfl_xor(t,32); acc2[h].w = t;
        m[h] = M; l[h] = lh;
    }

    float* pb = part + ((size_t)((b*NKV + n)*SPLITS + split)*4 + wave)*PSTRIDE;
    if (lane == 0){
#pragma unroll
        for (int h=0;h<4;h++){ pb[h] = m[h]; pb[4+h] = l[h]; }
    }
    if (kg == 0){
#pragma unroll
        for (int h=0;h<4;h++){
            *(float4*)(pb + 8 + h*HD + dl*4)      = acc1[h];
            *(float4*)(pb + 8 + h*HD + 64 + dl*4) = acc2[h];
        }
    }
}

// ---------------- combine the 64 wave-splits per (b, kv-head)
__global__ __launch_bounds__(256) void attn_combine(const float* __restrict__ part,
                                                    float* __restrict__ attn_out)
{
    const int bn  = blockIdx.x;   // b*8 + n
    const int tid = threadIdx.x;
    const float* pb = part + (size_t)bn*NPART*PSTRIDE;

    __shared__ float ml[NPART*8];
    {
        int i = tid*2;
        ml[i]   = pb[(size_t)(i>>3)*PSTRIDE + (i&7)];
        ml[i+1] = pb[(size_t)((i+1)>>3)*PSTRIDE + ((i+1)&7)];
    }
    __syncthreads();

    const int o = tid*2;
    const int h = o >> 7;
    const int d = o & 127;
    float M = -1e30f;
    for (int pI=0; pI<NPART; pI++) M = fmaxf(M, ml[pI*8+h]);
    float L = 0.f, a0 = 0.f, a1 = 0.f;
    for (int pI=0; pI<NPART; pI++){
        float w = __expf(ml[pI*8+h] - M);
        L += ml[pI*8+4+h]*w;
        float2 v = *(const float2*)(pb + (size_t)pI*PSTRIDE + 8 + h*HD + d);
        a0 += v.x*w; a1 += v.y*w;
    }
    float inv = 1.f / L;
    const int bb = bn >> 3, nn = bn & 7;
    float* op = attn_out + ((size_t)bb*NH + nn*4 + h)*HD + d;
    op[0] = a0*inv; op[1] = a1*inv;
}

// ---------------- reduce output-proj partials
__global__ __launch_bounds__(256) void o_reduce(const float* __restrict__ part,
                                                float* __restrict__ out)
{
    const int b   = blockIdx.x >> 3;
    const int seg = blockIdx.x & 7;
    const int j   = seg*512 + threadIdx.x*2;
    float a0 = 0.f, a1 = 0.f;
    const float* pp = part + (size_t)b*HIDDEN + j;
#pragma unroll 4
    for (int c=0;c<64;c++){
        float2 v = *(const float2*)(pp + (size_t)c*8*HIDDEN);
        a0 += v.x; a1 += v.y;
    }
    out[(size_t)b*HIDDEN + j]     = a0;
    out[(size_t)b*HIDDEN + j + 1] = a1;
}

extern "C" void kernel_launch(void* const* d_in, const int* in_sizes, int n_in,
                              void* d_out, int out_size, void* d_ws, size_t ws_size,
                              hipStream_t stream) {
    const float* hidden = (const float*)d_in[0];
    const float* wq     = (const float*)d_in[1];
    const float* wo     = (const float*)d_in[2];
    const float* cosb   = (const float*)d_in[3];
    const float* sinb   = (const float*)d_in[4];
    const float* knew   = (const float*)d_in[5];
    const float* vnew   = (const float*)d_in[6];
    const float* kc     = (const float*)d_in[7];
    const float* vc     = (const float*)d_in[8];
    float* out = (float*)d_out;

    float* ws        = (float*)d_ws;
    float* part      = ws;                    // 64*8*4096      = 2,097,152 floats
    float* q_rope    = ws + 2097152;          // 8*32*128       = 32,768
    float* attn_out  = q_rope + 32768;        // 8*32*128       = 32,768
    float* attn_part = attn_out + 32768;      // 64*64*520      = 2,129,920

    // 1) q = hidden @ wq (partials over 64 i-chunks)
    gemv_part<<<dim3(4,64), 256, 0, stream>>>(hidden, wq, part);
    // 2) reduce + RoPE
    q_reduce_rope<<<64, 256, 0, stream>>>(part, cosb, sinb, q_rope);
    // 3) flash-decoding attention over 8193 keys
    attn_split<<<dim3(SPLITS, NKV, 8), 256, 0, stream>>>(q_rope, kc, vc, knew, vnew,
                                                         cosb, sinb, attn_part);
    // 4) combine splits
    attn_combine<<<64, 256, 0, stream>>>(attn_part, attn_out);
    // 5) out = attn_out @ wo (partials)
    gemv_part<<<dim3(4,64), 256, 0, stream>>>(attn_out, wo, part);
    // 6) final reduce -> d_out
    o_reduce<<<64, 256, 0, stream>>>(part, out);
}

// Round 2
// 651.275 us; speedup vs baseline: 1.0086x; 1.0086x over previous
//
#include <hip/hip_runtime.h>

#define HIDDEN 4096
#define NH 32
#define NKV 8
#define HD 128
#define SKV 8192
#define SPLITS 16
#define NPART 64         // SPLITS * 4 waves
#define PSTRIDE 520      // 4 l (+4 pad) + 4*128 acc
#define SCALE 0.08838834764831845f

__device__ __forceinline__ float4 ld4(const float* p){ return *(const float4*)p; }

// ---------------- GEMV partial: part[c][b][j] = sum_{i in chunk c} vec[b][i]*mat[i][j]
// grid (4 jb, 64 c), 256 threads. chunk = 64 rows.
__global__ __launch_bounds__(256) void gemv_part(const float* __restrict__ vec,
                                                 const float* __restrict__ mat,
                                                 float* __restrict__ part)
{
    const int jb  = blockIdx.x;          // 0..3
    const int c   = blockIdx.y;          // 0..63
    const int tid = threadIdx.x;
    const int j0  = jb*1024 + tid*4;

    __shared__ float hid[64*8];          // hid[i][b] : i-major so reads are 2x b128 broadcast
    {
        int t = tid;                     // 512 elems, 2 per thread
        int b0 = t >> 6, i0 = t & 63;
        hid[i0*8 + b0] = vec[(size_t)b0*HIDDEN + c*64 + i0];
        t += 256;
        int b1 = t >> 6, i1 = t & 63;
        hid[i1*8 + b1] = vec[(size_t)b1*HIDDEN + c*64 + i1];
    }
    __syncthreads();

    float4 acc[8];
#pragma unroll
    for (int b=0;b<8;b++) acc[b] = make_float4(0.f,0.f,0.f,0.f);

    const float* mp = mat + (size_t)c*64*HIDDEN + j0;
#pragma unroll 8
    for (int ii=0; ii<64; ii++) {
        float4 w  = ld4(mp + (size_t)ii*HIDDEN);
        float4 h0 = *(const float4*)&hid[ii*8];      // b0..3
        float4 h1 = *(const float4*)&hid[ii*8+4];    // b4..7
        acc[0].x += h0.x*w.x; acc[0].y += h0.x*w.y; acc[0].z += h0.x*w.z; acc[0].w += h0.x*w.w;
        acc[1].x += h0.y*w.x; acc[1].y += h0.y*w.y; acc[1].z += h0.y*w.z; acc[1].w += h0.y*w.w;
        acc[2].x += h0.z*w.x; acc[2].y += h0.z*w.y; acc[2].z += h0.z*w.z; acc[2].w += h0.z*w.w;
        acc[3].x += h0.w*w.x; acc[3].y += h0.w*w.y; acc[3].z += h0.w*w.z; acc[3].w += h0.w*w.w;
        acc[4].x += h1.x*w.x; acc[4].y += h1.x*w.y; acc[4].z += h1.x*w.z; acc[4].w += h1.x*w.w;
        acc[5].x += h1.y*w.x; acc[5].y += h1.y*w.y; acc[5].z += h1.y*w.z; acc[5].w += h1.y*w.w;
        acc[6].x += h1.z*w.x; acc[6].y += h1.z*w.y; acc[6].z += h1.z*w.z; acc[6].w += h1.z*w.w;
        acc[7].x += h1.w*w.x; acc[7].y += h1.w*w.y; acc[7].z += h1.w*w.z; acc[7].w += h1.w*w.w;
    }
#pragma unroll
    for (int b=0;b<8;b++)
        *(float4*)(part + ((size_t)(c*8+b))*HIDDEN + j0) = acc[b];
}

// ---------------- reduce q partials + RoPE
// grid (8b * 32 jseg) = 256 blocks, 256 thr = 128 j x 2 cg (32 chunks each)
__global__ __launch_bounds__(256) void q_reduce_rope(const float* __restrict__ part,
                                                     const float* __restrict__ cosb,
                                                     const float* __restrict__ sinb,
                                                     float* __restrict__ q_rope)
{
    const int b    = blockIdx.x >> 5;
    const int jseg = blockIdx.x & 31;
    const int tid  = threadIdx.x;
    const int jl   = tid & 127;
    const int cg   = tid >> 7;

    float a = 0.f;
    const float* pp = part + (size_t)(cg*32*8 + b)*HIDDEN + jseg*128 + jl;
#pragma unroll 8
    for (int c=0;c<32;c++) a += pp[(size_t)c*8*HIDDEN];

    __shared__ float lds[256];
    __shared__ float sum[128];
    lds[tid] = a;
    __syncthreads();
    if (tid < 128) sum[tid] = lds[tid] + lds[tid+128];
    __syncthreads();
    if (tid < 128) {
        const int d = tid;              // jseg*128 aligned -> head dim = tid
        float x = sum[d];
        float p = sum[d ^ 64];
        float cv = cosb[b*HD + d], sv = sinb[b*HD + d];
        float r = (d < 64) ? (x*cv - p*sv) : (x*cv + p*sv);
        q_rope[(size_t)b*HIDDEN + jseg*128 + d] = r;
    }
}

// ---------------- attention split kernel: branch-free raw-exp flash decoding
// lane: kg = lane>>4 (key in 4-key group), dl = lane&15 (dims dl*4..+4 and 64+dl*4..+4)
__global__ __launch_bounds__(256) void attn_split(const float* __restrict__ qr,
                                                  const float* __restrict__ kc,
                                                  const float* __restrict__ vc,
                                                  float* __restrict__ part)
{
    const int split = blockIdx.x;
    const int n     = blockIdx.y;
    const int b     = blockIdx.z;
    const int tid   = threadIdx.x;
    const int wave  = tid >> 6;
    const int lane  = tid & 63;
    const int kg    = lane >> 4;
    const int dl    = lane & 15;

    float4 q1[4], q2[4];
    const float* qb = qr + ((size_t)b*NH + n*4)*HD;
#pragma unroll
    for (int h=0;h<4;h++){
        float4 x = ld4(qb + h*HD + dl*4);
        float4 y = ld4(qb + h*HD + 64 + dl*4);
        q1[h] = make_float4(x.x*SCALE, x.y*SCALE, x.z*SCALE, x.w*SCALE);
        q2[h] = make_float4(y.x*SCALE, y.y*SCALE, y.z*SCALE, y.w*SCALE);
    }
    float l[4] = {0.f,0.f,0.f,0.f};
    float4 acc1[4], acc2[4];
#pragma unroll
    for (int h=0;h<4;h++){
        acc1[h] = make_float4(0.f,0.f,0.f,0.f);
        acc2[h] = make_float4(0.f,0.f,0.f,0.f);
    }

    const float* kb = kc + ((size_t)b*SKV*NKV + n)*HD;
    const float* vb = vc + ((size_t)b*SKV*NKV + n)*HD;

    int t0 = split*512 + wave*16;
    for (int iter=0; iter<8; iter++, t0 += 64) {
#pragma unroll
        for (int it=0; it<4; it++){
            const int k = t0 + it*4 + kg;
            const float* kp = kb + (size_t)k*(NKV*HD);
            const float* vp = vb + (size_t)k*(NKV*HD);
            float4 k1 = ld4(kp + dl*4);
            float4 k2 = ld4(kp + 64 + dl*4);
            float4 v1 = ld4(vp + dl*4);
            float4 v2 = ld4(vp + 64 + dl*4);
            float p[4];
#pragma unroll
            for (int h=0;h<4;h++){
                float sp = q1[h].x*k1.x + q1[h].y*k1.y + q1[h].z*k1.z + q1[h].w*k1.w
                         + q2[h].x*k2.x + q2[h].y*k2.y + q2[h].z*k2.z + q2[h].w*k2.w;
                sp += __shfl_xor(sp, 1);
                sp += __shfl_xor(sp, 2);
                sp += __shfl_xor(sp, 4);
                sp += __shfl_xor(sp, 8);
                p[h] = __expf(sp);
                l[h] += p[h];
            }
#pragma unroll
            for (int h=0;h<4;h++){
                float ph = p[h];
                acc1[h].x += ph*v1.x; acc1[h].y += ph*v1.y;
                acc1[h].z += ph*v1.z; acc1[h].w += ph*v1.w;
                acc2[h].x += ph*v2.x; acc2[h].y += ph*v2.y;
                acc2[h].z += ph*v2.z; acc2[h].w += ph*v2.w;
            }
        }
    }

    // combine the 4 key-groups within the wave (pure adds)
#pragma unroll
    for (int h=0;h<4;h++){
        float t;
        t = l[h];      t += __shfl_xor(t,16); t += __shfl_xor(t,32); l[h] = t;
        t = acc1[h].x; t += __shfl_xor(t,16); t += __shfl_xor(t,32); acc1[h].x = t;
        t = acc1[h].y; t += __shfl_xor(t,16); t += __shfl_xor(t,32); acc1[h].y = t;
        t = acc1[h].z; t += __shfl_xor(t,16); t += __shfl_xor(t,32); acc1[h].z = t;
        t = acc1[h].w; t += __shfl_xor(t,16); t += __shfl_xor(t,32); acc1[h].w = t;
        t = acc2[h].x; t += __shfl_xor(t,16); t += __shfl_xor(t,32); acc2[h].x = t;
        t = acc2[h].y; t += __shfl_xor(t,16); t += __shfl_xor(t,32); acc2[h].y = t;
        t = acc2[h].z; t += __shfl_xor(t,16); t += __shfl_xor(t,32); acc2[h].z = t;
        t = acc2[h].w; t += __shfl_xor(t,16); t += __shfl_xor(t,32); acc2[h].w = t;
    }

    float* pb = part + ((size_t)((b*NKV + n)*SPLITS + split)*4 + wave)*PSTRIDE;
    if (lane == 0){
#pragma unroll
        for (int h=0;h<4;h++) pb[h] = l[h];
    }
    if (kg == 0){
#pragma unroll
        for (int h=0;h<4;h++){
            *(float4*)(pb + 8 + h*HD + dl*4)      = acc1[h];
            *(float4*)(pb + 8 + h*HD + 64 + dl*4) = acc2[h];
        }
    }
}

// ---------------- combine 64 partials per (b,n) + the single new RoPE'd key
__global__ __launch_bounds__(256) void attn_combine(const float* __restrict__ part,
                                                    const float* __restrict__ qr,
                                                    const float* __restrict__ knew,
                                                    const float* __restrict__ vnew,
                                                    const float* __restrict__ cosb,
                                                    const float* __restrict__ sinb,
                                                    float* __restrict__ attn_out)
{
    const int bn  = blockIdx.x;   // b*8 + n
    const int b   = bn >> 3;
    const int n   = bn & 7;
    const int tid = threadIdx.x;
    const int wave = tid >> 6;
    const int lane = tid & 63;
    const float* pp = part + (size_t)bn*NPART*PSTRIDE;

    __shared__ float sm[4];       // exp(score_newkey) per head
    __shared__ float lds_l[NPART*4];

    // phase 1a: preload l values (256 = 64 partials x 4 heads)
    lds_l[tid] = pp[(size_t)(tid>>2)*PSTRIDE + (tid&3)];

    // phase 1b: new-key RoPE + score, wave w handles head h=w
    {
        const float* kn = knew + (size_t)bn*HD;
        const float* cb = cosb + (size_t)b*HD;
        const float* sb = sinb + (size_t)b*HD;
        const float* qh = qr + ((size_t)b*NH + n*4 + wave)*HD;
        float k_lo = kn[lane], k_hi = kn[lane+64];
        float kr1 = k_lo*cb[lane]    - k_hi*sb[lane];
        float kr2 = k_hi*cb[lane+64] + k_lo*sb[lane+64];
        float sp = (qh[lane]*kr1 + qh[lane+64]*kr2) * SCALE;
        sp += __shfl_xor(sp, 1);
        sp += __shfl_xor(sp, 2);
        sp += __shfl_xor(sp, 4);
        sp += __shfl_xor(sp, 8);
        sp += __shfl_xor(sp, 16);
        sp += __shfl_xor(sp, 32);
        if (lane == 0) sm[wave] = __expf(sp);
    }
    __syncthreads();

    const int o = tid*2;
    const int h = o >> 7;
    const int d = o & 127;
    const float wn = sm[h];
    float L = wn;
#pragma unroll 8
    for (int p=0; p<NPART; p++) L += lds_l[p*4+h];

    const float* vn = vnew + (size_t)bn*HD;
    float a0 = wn * vn[d];
    float a1 = wn * vn[d+1];
    const float* ap = pp + 8 + h*HD + d;
#pragma unroll 8
    for (int p=0; p<NPART; p++){
        float2 v = *(const float2*)(ap + (size_t)p*PSTRIDE);
        a0 += v.x; a1 += v.y;
    }
    const float inv = 1.f / L;
    float* op = attn_out + ((size_t)b*NH + n*4 + h)*HD + d;
    op[0] = a0*inv; op[1] = a1*inv;
}

// ---------------- reduce output-proj partials -> d_out
__global__ __launch_bounds__(256) void o_reduce(const float* __restrict__ part,
                                                float* __restrict__ out)
{
    const int b    = blockIdx.x >> 5;
    const int jseg = blockIdx.x & 31;
    const int tid  = threadIdx.x;
    const int jl   = tid & 127;
    const int cg   = tid >> 7;

    float a = 0.f;
    const float* pp = part + (size_t)(cg*32*8 + b)*HIDDEN + jseg*128 + jl;
#pragma unroll 8
    for (int c=0;c<32;c++) a += pp[(size_t)c*8*HIDDEN];

    __shared__ float lds[256];
    lds[tid] = a;
    __syncthreads();
    if (tid < 128)
        out[(size_t)b*HIDDEN + jseg*128 + tid] = lds[tid] + lds[tid+128];
}

extern "C" void kernel_launch(void* const* d_in, const int* in_sizes, int n_in,
                              void* d_out, int out_size, void* d_ws, size_t ws_size,
                              hipStream_t stream) {
    const float* hidden = (const float*)d_in[0];
    const float* wq     = (const float*)d_in[1];
    const float* wo     = (const float*)d_in[2];
    const float* cosb   = (const float*)d_in[3];
    const float* sinb   = (const float*)d_in[4];
    const float* knew   = (const float*)d_in[5];
    const float* vnew   = (const float*)d_in[6];
    const float* kc     = (const float*)d_in[7];
    const float* vc     = (const float*)d_in[8];
    float* out = (float*)d_out;

    float* ws        = (float*)d_ws;
    float* part      = ws;                    // 64*8*4096      = 2,097,152 floats
    float* q_rope    = ws + 2097152;          // 8*32*128       = 32,768
    float* attn_out  = q_rope + 32768;        // 8*32*128       = 32,768
    float* attn_part = attn_out + 32768;      // 64*64*520      = 2,129,920

    // 1) q = hidden @ wq (partials over 64 i-chunks)
    gemv_part<<<dim3(4,64), 256, 0, stream>>>(hidden, wq, part);
    // 2) reduce + RoPE
    q_reduce_rope<<<256, 256, 0, stream>>>(part, cosb, sinb, q_rope);
    // 3) branch-free flash-decoding over the 8192 cached keys
    attn_split<<<dim3(SPLITS, NKV, 8), 256, 0, stream>>>(q_rope, kc, vc, attn_part);
    // 4) combine splits + new key
    attn_combine<<<64, 256, 0, stream>>>(attn_part, q_rope, knew, vnew, cosb, sinb, attn_out);
    // 5) out = attn_out @ wo (partials)
    gemv_part<<<dim3(4,64), 256, 0, stream>>>(attn_out, wo, part);
    // 6) final reduce -> d_out
    o_reduce<<<256, 256, 0, stream>>>(part, out);
}